// Round 4
// baseline (320.845 us; speedup 1.0000x reference)
//
#include <hip/hip_runtime.h>
#include <stdint.h>

#define I_DIM 2048
#define O_DIM 8192
#define T_TOK 512
#define NSTR  64
#define BK    64
#define NSTEP (I_DIM / BK)

#define TILE_B 32768  // bytes per (stripe,step): [hi 16KB | lo 16KB], pre-swizzled

// workspace layout
#define WT_OFF   ((size_t)0)                       // 64MB tiles
#define XC_OFF   ((size_t)67108864)                // 4MB xc f32
#define MK_OFF   ((size_t)71303168)                // 8MB mask u64[64][512][32]
#define PM_OFF   ((size_t)79691776)                // 2MB pm_part f32[64][8192]
#define PMB_OFF  ((size_t)81788928)                // 32KB pmb f32[8192]
#define CNT_OFF  ((size_t)81821696)                // 2KB counts i32[512]

typedef __attribute__((ext_vector_type(8))) short bf16x8;
typedef __attribute__((ext_vector_type(4))) float f32x4;

__device__ __forceinline__ void gload16(const void* g, void* l) {
  __builtin_amdgcn_global_load_lds(
      (const __attribute__((address_space(1))) void*)g,
      (__attribute__((address_space(3))) void*)l, 16, 0, 0);
}

// k0: xc = x - mu (elementwise, float4); zero counts.
__global__ void cwic_xc(const float* __restrict__ x, const float* __restrict__ mu,
                        float* __restrict__ xc, int* __restrict__ counts) {
  int idx = blockIdx.x * 256 + threadIdx.x;  // 262144 float4s
  float4 xv = ((const float4*)x)[idx];
  float4 mv = ((const float4*)mu)[idx & 511];
  float4 r;
  r.x = xv.x - mv.x; r.y = xv.y - mv.y; r.z = xv.z - mv.z; r.w = xv.w - mv.w;
  ((float4*)xc)[idx] = r;
  if (idx < T_TOK) counts[idx] = 0;
}

// k1: bit-packed mask via ballot + popcount into counts.
// mask[n][t][c] (u64): bit l = |xc[t][c*64+l]| > thresholds[n][c*64+l]*std[c*64+l]
__global__ __launch_bounds__(256) void cwic_mask(
    const float* __restrict__ xc, const float* __restrict__ thresholds,
    const float* __restrict__ stdv, unsigned long long* __restrict__ mask,
    int* __restrict__ counts) {
  const int n = blockIdx.x >> 3, tc = blockIdx.x & 7;
  const int wave = threadIdx.x >> 6, lane = threadIdx.x & 63;
  float thrv[32];
  #pragma unroll
  for (int c = 0; c < 32; ++c)
    thrv[c] = thresholds[(size_t)n * I_DIM + c * 64 + lane] * stdv[c * 64 + lane];
  for (int tt = 0; tt < 16; ++tt) {
    const int t = tc * 64 + wave * 16 + tt;
    const float* xr = xc + (size_t)t * I_DIM;
    int s = 0;
    #pragma unroll
    for (int c = 0; c < 32; ++c) {
      float v = xr[c * 64 + lane];
      unsigned long long bm = __ballot(fabsf(v) > thrv[c]);
      if (lane == 0) mask[((size_t)n * T_TOK + t) * 32 + c] = bm;
      s += __popcll(bm);
    }
    if (lane == 0) atomicAdd(&counts[t], s);
  }
}

// k2: weight split f32 -> bf16 hi/lo tiles (pre-swizzled LDS image, hi|lo contiguous
// per (n,step)) + post_mu partial sums.
__global__ __launch_bounds__(256) void cwic_wprep(const float* __restrict__ w,
                                                  const float* __restrict__ mu,
                                                  char* __restrict__ wt,
                                                  float* __restrict__ pm_part) {
  const int bp = blockIdx.x;  // 2048 = 64 stripes x 32 steps
  const int n = bp >> 5, step = bp & 31;
  const int tid = threadIdx.x;
  const int o = tid & 127, kh = tid >> 7;
  const float* wp = w + (size_t)(step * BK + kh * 32) * O_DIM + n * 128 + o;
  char* tb = wt + (size_t)bp * TILE_B;
  const int rowb = o * 128;
  const int swz = (o & 7) << 4;
  float pm = 0.0f;
  #pragma unroll
  for (int g = 0; g < 4; ++g) {
    unsigned hv[4], lv[4];
    unsigned hprev = 0, lprev = 0;
    #pragma unroll
    for (int e = 0; e < 8; ++e) {
      const int irow = step * BK + kh * 32 + g * 8 + e;
      float v = wp[(size_t)(g * 8 + e) * O_DIM];
      pm += mu[irow] * v;
      unsigned u = __builtin_bit_cast(unsigned, v);
      unsigned r = u + 0x7fffu + ((u >> 16) & 1u);
      unsigned short h = (unsigned short)(r >> 16);
      float hif = __builtin_bit_cast(float, r & 0xffff0000u);
      unsigned short lo = (unsigned short)(__builtin_bit_cast(unsigned, v - hif) >> 16);
      if ((e & 1) == 0) { hprev = h; lprev = lo; }
      else {
        hv[e >> 1] = hprev | (((unsigned)h) << 16);
        lv[e >> 1] = lprev | (((unsigned)lo) << 16);
      }
    }
    *(__attribute__((ext_vector_type(4))) int*)(tb + rowb + ((kh * 64 + g * 16) ^ swz)) =
        *(__attribute__((ext_vector_type(4))) int*)hv;
    *(__attribute__((ext_vector_type(4))) int*)(tb + 16384 + rowb + ((kh * 64 + g * 16) ^ swz)) =
        *(__attribute__((ext_vector_type(4))) int*)lv;
  }
  pm_part[(size_t)(step * 2 + kh) * O_DIM + n * 128 + o] = pm;
}

// k3: pmb[o] = bias[o] + sum_s pm_part[s][o]  (fixed order, deterministic)
__global__ void cwic_pmb(const float* __restrict__ pm_part,
                         const float* __restrict__ bias, float* __restrict__ pmb) {
  int o = blockIdx.x * 256 + threadIdx.x;
  float s = bias[o];
  #pragma unroll 8
  for (int j = 0; j < 64; ++j) s += pm_part[(size_t)j * O_DIM + o];
  pmb[o] = s;
}

// k4: masked GEMM. A = (mask? xc : 0) built in-register (hi/lo bf16 split, 3 MFMA
// products); B double-buffered in LDS via global_load_lds with counted vmcnt +
// raw barriers (one barrier per K-step, never vmcnt(0) in the loop).
__global__ __launch_bounds__(256, 2) void cwic_gemm4(
    const float* __restrict__ xc, const char* __restrict__ wt,
    const unsigned long long* __restrict__ mask, const float* __restrict__ pmb,
    float* __restrict__ y) {
  extern __shared__ char smem[];  // [2][32768] B double-buffer
  const int b = blockIdx.x;
  // XCD swizzle: 8 token-tiles of one stripe per XCD -> B tiles L2-hot.
  const int nid = (b & 7) * 64 + (b >> 3);
  const int n = nid >> 3, tt = nid & 7;
  const int trow0 = tt * 64, ocol0 = n * 128;
  const int tid = threadIdx.x;
  const int lane = tid & 63, wid = tid >> 6;
  const int wr = wid >> 1, wc = wid & 1;
  const int l15 = lane & 15, l4 = lane >> 4;

  const int r0 = trow0 + wr * 32 + l15;  // mi=0 token row
  const int r1 = r0 + 16;                // mi=1 token row
  const float* x0p = xc + (size_t)r0 * I_DIM + l4 * 8;
  const float* x1p = xc + (size_t)r1 * I_DIM + l4 * 8;
  const unsigned long long* m0p = mask + ((size_t)n * T_TOK + r0) * 32;
  const unsigned long long* m1p = mask + ((size_t)n * T_TOK + r1) * 32;
  const char* wtb = wt + (size_t)(n * 32) * TILE_B;

  f32x4 acc[2][4];
  #pragma unroll
  for (int mi = 0; mi < 2; ++mi)
    #pragma unroll
    for (int ni = 0; ni < 4; ++ni) acc[mi][ni] = (f32x4)(0.0f);

  float4 xa[8], xb[8];            // [mi*4 + s32*2 + q]
  unsigned long long ma[2], mb[2];

#define LOADX(X, M, st)                                            \
  {                                                                \
    const int kk_ = (st) * BK;                                     \
    _Pragma("unroll") for (int mi_ = 0; mi_ < 2; ++mi_) {          \
      const float* xp_ = mi_ ? x1p : x0p;                          \
      _Pragma("unroll") for (int s3_ = 0; s3_ < 2; ++s3_) {        \
        X[mi_ * 4 + s3_ * 2 + 0] = *(const float4*)(xp_ + kk_ + s3_ * 32);     \
        X[mi_ * 4 + s3_ * 2 + 1] = *(const float4*)(xp_ + kk_ + s3_ * 32 + 4); \
      }                                                            \
    }                                                              \
    M[0] = m0p[st];                                                \
    M[1] = m1p[st];                                                \
  }

  // ---- prologue: issue B(0), then x(0)/mask(0); drain B(0) only ----
  {
    const char* bs = wtb + tid * 16;
    #pragma unroll
    for (int j = 0; j < 8; ++j) gload16(bs + j * 4096, smem + j * 4096 + tid * 16);
  }
  LOADX(xa, ma, 0);
  asm volatile("s_waitcnt vmcnt(10)" ::: "memory");
  __builtin_amdgcn_s_barrier();

  int cur = 0;

#define ITER(st, XU, MU_, XP, MP)                                              \
  {                                                                            \
    const int s1_ = ((st) < NSTEP - 1) ? (st) + 1 : (st);                      \
    /* 1. issue B(step+1) into buf^1 */                                        \
    {                                                                          \
      const char* bs_ = wtb + (size_t)s1_ * TILE_B + tid * 16;                 \
      char* bd_ = smem + (cur ^ 1) * TILE_B + tid * 16;                        \
      _Pragma("unroll") for (int j_ = 0; j_ < 8; ++j_)                         \
          gload16(bs_ + j_ * 4096, bd_ + j_ * 4096);                           \
    }                                                                          \
    /* 2. prefetch xc/mask for step+1 (regs) */                                \
    LOADX(XP, MP, s1_);                                                        \
    /* 3-5. A-build + ds_read B + MFMA */                                      \
    {                                                                          \
      const char* bb_ = smem + cur * TILE_B;                                   \
      __builtin_amdgcn_s_setprio(1);                                           \
      _Pragma("unroll") for (int s32 = 0; s32 < 2; ++s32) {                    \
        bf16x8 afh[2], afl[2];                                                 \
        _Pragma("unroll") for (int mi = 0; mi < 2; ++mi) {                     \
          unsigned m32 = (unsigned)(MU_[mi] >> (s32 * 32 + l4 * 8));           \
          const float4 va = XU[mi * 4 + s32 * 2];                              \
          const float4 vb = XU[mi * 4 + s32 * 2 + 1];                          \
          float xs[8] = {va.x, va.y, va.z, va.w, vb.x, vb.y, vb.z, vb.w};      \
          _Pragma("unroll") for (int e = 0; e < 8; ++e) {                      \
            float a = ((m32 >> e) & 1u) ? xs[e] : 0.0f;                        \
            unsigned u = __builtin_bit_cast(unsigned, a);                      \
            unsigned r = u + 0x7fffu + ((u >> 16) & 1u);                       \
            afh[mi][e] = (short)(r >> 16);                                     \
            float hif = __builtin_bit_cast(float, r & 0xffff0000u);            \
            afl[mi][e] = (short)(__builtin_bit_cast(unsigned, a - hif) >> 16); \
          }                                                                    \
        }                                                                      \
        _Pragma("unroll") for (int ni = 0; ni < 4; ++ni) {                     \
          const int o_ = wc * 64 + ni * 16 + l15;                              \
          const int ad_ = o_ * 128 + (((s32 * 64) + l4 * 16) ^ ((o_ & 7) << 4)); \
          bf16x8 bh = *(const bf16x8*)(bb_ + ad_);                             \
          bf16x8 bl = *(const bf16x8*)(bb_ + 16384 + ad_);                     \
          _Pragma("unroll") for (int mi = 0; mi < 2; ++mi) {                   \
            acc[mi][ni] = __builtin_amdgcn_mfma_f32_16x16x32_bf16(afh[mi], bh, acc[mi][ni], 0, 0, 0); \
            acc[mi][ni] = __builtin_amdgcn_mfma_f32_16x16x32_bf16(afh[mi], bl, acc[mi][ni], 0, 0, 0); \
            acc[mi][ni] = __builtin_amdgcn_mfma_f32_16x16x32_bf16(afl[mi], bh, acc[mi][ni], 0, 0, 0); \
          }                                                                    \
        }                                                                      \
      }                                                                        \
      __builtin_amdgcn_s_setprio(0);                                           \
    }                                                                          \
    /* 6-7. counted drain of B(step+1) (xc/mask stay in flight), barrier */    \
    asm volatile("s_waitcnt vmcnt(10)" ::: "memory");                          \
    __builtin_amdgcn_sched_barrier(0);                                         \
    __builtin_amdgcn_s_barrier();                                              \
    cur ^= 1;                                                                  \
  }

  for (int sp = 0; sp < NSTEP; sp += 2) {
    ITER(sp, xa, ma, xb, mb);
    ITER(sp + 1, xb, mb, xa, ma);
  }

  // ---- epilogue: y = acc + (post_mu + bias); C/D layout m89-verified ----
  #pragma unroll
  for (int ni = 0; ni < 4; ++ni) {
    const int o = ocol0 + wc * 64 + ni * 16 + l15;
    const float pv = pmb[o];
    #pragma unroll
    for (int mi = 0; mi < 2; ++mi) {
      const int row0 = trow0 + wr * 32 + mi * 16 + l4 * 4;
      #pragma unroll
      for (int r = 0; r < 4; ++r) {
        y[(size_t)(row0 + r) * O_DIM + o] = acc[mi][ni][r] + pv;
      }
    }
  }
#undef ITER
#undef LOADX
}

// k5: flops outputs. flops_sparse = 16777216 * cnt/(64*2048) = 128*cnt (exact).
__global__ void cwic_fin(const int* __restrict__ counts, float* __restrict__ outF) {
  int t = blockIdx.x * 256 + threadIdx.x;
  outF[t] = 16777216.0f;
  outF[T_TOK + t] = 128.0f * (float)counts[t];
}

extern "C" void kernel_launch(void* const* d_in, const int* in_sizes, int n_in,
                              void* d_out, int out_size, void* d_ws, size_t ws_size,
                              hipStream_t stream) {
  const float* x = (const float*)d_in[0];
  const float* w = (const float*)d_in[1];
  const float* bias = (const float*)d_in[2];
  const float* thresholds = (const float*)d_in[3];
  const float* mu = (const float*)d_in[4];
  const float* stdv = (const float*)d_in[5];
  float* y = (float*)d_out;

  char* ws = (char*)d_ws;
  char* wt = ws + WT_OFF;
  float* xc = (float*)(ws + XC_OFF);
  unsigned long long* mask = (unsigned long long*)(ws + MK_OFF);
  float* pm_part = (float*)(ws + PM_OFF);
  float* pmb = (float*)(ws + PMB_OFF);
  int* counts = (int*)(ws + CNT_OFF);

  cwic_xc<<<1024, 256, 0, stream>>>(x, mu, xc, counts);
  cwic_mask<<<512, 256, 0, stream>>>(xc, thresholds, stdv, mask, counts);
  cwic_wprep<<<NSTR * NSTEP, 256, 0, stream>>>(w, mu, wt, pm_part);
  cwic_pmb<<<32, 256, 0, stream>>>(pm_part, bias, pmb);
  cwic_gemm4<<<512, 256, 2 * TILE_B, stream>>>(xc, wt, mask, pmb, y);
  cwic_fin<<<2, 256, 0, stream>>>(counts, y + (size_t)T_TOK * O_DIM);
}

// Round 6
// 168.104 us; speedup vs baseline: 1.9086x; 1.9086x over previous
//
#include <hip/hip_runtime.h>
#include <stdint.h>

#define I_DIM 2048
#define O_DIM 8192
#define T_TOK 512
#define NSTR  64
#define BK    64
#define NSTEP (I_DIM / BK)

#define TILE_B 32768  // bytes per (stripe,step): [hi 16KB | lo 16KB], pre-swizzled

// workspace layout
#define WT_OFF   ((size_t)0)             // 64MB weight tiles
#define XC_OFF   ((size_t)67108864)      // 4MB xc f32
#define THR_OFF  ((size_t)71303168)      // 512KB thrs f32[64][2048]
#define PM_OFF   ((size_t)71827456)      // 2MB pm_part f32[64][8192]
#define PMB_OFF  ((size_t)73924608)      // 32KB pmb f32[8192]
#define CNT_OFF  ((size_t)73957376)      // 2KB counts i32[512]

typedef __attribute__((ext_vector_type(8))) short bf16x8;
typedef __attribute__((ext_vector_type(4))) float f32x4;
typedef __attribute__((ext_vector_type(4))) int i32x4;

__device__ __forceinline__ void gload16(const void* g, void* l) {
  __builtin_amdgcn_global_load_lds(
      (const __attribute__((address_space(1))) void*)g,
      (__attribute__((address_space(3))) void*)l, 16, 0, 0);
}

// k0: thrs[n][i] = thresholds[n][i]*std[i] (exact ref arithmetic); zero counts.
__global__ void cwic_init(const float* __restrict__ thresholds,
                          const float* __restrict__ stdv,
                          float* __restrict__ thrs, int* __restrict__ counts) {
  int idx = blockIdx.x * 256 + threadIdx.x;  // covers 64*2048
  thrs[idx] = thresholds[idx] * stdv[idx & (I_DIM - 1)];
  if (idx < T_TOK) counts[idx] = 0;
}

// k1: xc = x - mu (exact ref arithmetic).
__global__ void cwic_xc(const float* __restrict__ x, const float* __restrict__ mu,
                        float* __restrict__ xc) {
  int idx = blockIdx.x * 256 + threadIdx.x;  // 262144 float4s
  float4 xv = ((const float4*)x)[idx];
  float4 mv = ((const float4*)mu)[idx & 511];
  float4 r;
  r.x = xv.x - mv.x; r.y = xv.y - mv.y; r.z = xv.z - mv.z; r.w = xv.w - mv.w;
  ((float4*)xc)[idx] = r;
}

// k2: weight split f32 -> bf16 hi/lo tiles (pre-swizzled LDS image) + post_mu partials.
__global__ __launch_bounds__(256) void cwic_wprep(const float* __restrict__ w,
                                                  const float* __restrict__ mu,
                                                  char* __restrict__ wt,
                                                  float* __restrict__ pm_part) {
  const int bp = blockIdx.x;  // 2048 = 64 stripes x 32 steps
  const int n = bp >> 5, step = bp & 31;
  const int tid = threadIdx.x;
  const int o = tid & 127, kh = tid >> 7;
  const float* wp = w + (size_t)(step * BK + kh * 32) * O_DIM + n * 128 + o;
  char* tb = wt + (size_t)bp * TILE_B;
  const int rowb = o * 128;
  const int swz = (o & 7) << 4;
  float pm = 0.0f;
  #pragma unroll
  for (int g = 0; g < 4; ++g) {
    unsigned hv[4], lv[4];
    unsigned hprev = 0, lprev = 0;
    #pragma unroll
    for (int e = 0; e < 8; ++e) {
      const int irow = step * BK + kh * 32 + g * 8 + e;
      float v = wp[(size_t)(g * 8 + e) * O_DIM];
      pm += mu[irow] * v;
      unsigned u = __builtin_bit_cast(unsigned, v);
      unsigned r = u + 0x7fffu + ((u >> 16) & 1u);
      unsigned short h = (unsigned short)(r >> 16);
      float hif = __builtin_bit_cast(float, r & 0xffff0000u);
      unsigned short lo = (unsigned short)(__builtin_bit_cast(unsigned, v - hif) >> 16);
      if ((e & 1) == 0) { hprev = h; lprev = lo; }
      else {
        hv[e >> 1] = hprev | (((unsigned)h) << 16);
        lv[e >> 1] = lprev | (((unsigned)lo) << 16);
      }
    }
    *(i32x4*)(tb + rowb + ((kh * 64 + g * 16) ^ swz)) = *(i32x4*)hv;
    *(i32x4*)(tb + 16384 + rowb + ((kh * 64 + g * 16) ^ swz)) = *(i32x4*)lv;
  }
  pm_part[(size_t)(step * 2 + kh) * O_DIM + n * 128 + o] = pm;
}

// k3: pmb[o] = bias[o] + sum_s pm_part[s][o] (fixed order, deterministic)
__global__ void cwic_pmb(const float* __restrict__ pm_part,
                         const float* __restrict__ bias, float* __restrict__ pmb) {
  int o = blockIdx.x * 256 + threadIdx.x;
  float s = bias[o];
  #pragma unroll 8
  for (int j = 0; j < 64; ++j) s += pm_part[(size_t)j * O_DIM + o];
  pmb[o] = s;
}

// k4: masked GEMM. A = (|xc|>thr ? xc : 0) built in-register (integer hi/lo bf16
// split, 3 MFMA products); B double-buffered in LDS via global_load_lds; counted
// vmcnt (never 0 in loop) + 2 barriers/step (T3/T4). Counts fused into A-build.
// vmcnt accounting (T4): at the explicit wait, ops newer than B(step)'s 8 gloads
// are 12 xc/thr prefetch + 8 B(step+1) = 20 -> vmcnt(20) drains exactly B(step).
__global__ __launch_bounds__(256, 2) void cwic_gemm5(
    const float* __restrict__ xc, const char* __restrict__ wt,
    const float* __restrict__ thrs, const float* __restrict__ pmb,
    float* __restrict__ y, int* __restrict__ counts) {
  extern __shared__ char smem[];  // [2][32768] B double-buffer
  const int b = blockIdx.x;
  // XCD swizzle: the 8 token-tile blocks of one stripe share an XCD -> B L2-hot.
  const int nid = (b & 7) * 64 + (b >> 3);
  const int n = nid >> 3, tt = nid & 7;
  const int trow0 = tt * 64, ocol0 = n * 128;
  const int tid = threadIdx.x;
  const int lane = tid & 63, wid = tid >> 6;
  const int wr = wid >> 1, wc = wid & 1;
  const int l15 = lane & 15, l4 = lane >> 4;

  const int r0 = trow0 + wr * 32 + l15, r1 = r0 + 16;
  const float4* xp0 = (const float4*)xc + (size_t)r0 * (I_DIM / 4) + l4 * 2;
  const float4* xp1 = (const float4*)xc + (size_t)r1 * (I_DIM / 4) + l4 * 2;
  const float4* thg = (const float4*)(thrs + (size_t)n * I_DIM) + l4 * 2;
  const char* wtb = wt + (size_t)(n * NSTEP) * TILE_B;

  f32x4 acc[2][4];
  #pragma unroll
  for (int mi = 0; mi < 2; ++mi)
    #pragma unroll
    for (int ni = 0; ni < 4; ++ni) acc[mi][ni] = (f32x4)(0.0f);

  float4 xA[8], xB[8];  // [mi*4 + s32*2 + q]
  float4 tA[4], tB[4];  // [s32*2 + q]
  int cnt0 = 0, cnt1 = 0;

  // ---- prologue: issue xc(0)/thr(0), then B(0); full drain once ----
  #pragma unroll
  for (int mi = 0; mi < 2; ++mi)
    #pragma unroll
    for (int s3 = 0; s3 < 2; ++s3)
      #pragma unroll
      for (int q = 0; q < 2; ++q)
        xA[mi * 4 + s3 * 2 + q] = (mi ? xp1 : xp0)[s3 * 8 + q];
  #pragma unroll
  for (int s3 = 0; s3 < 2; ++s3)
    #pragma unroll
    for (int q = 0; q < 2; ++q) tA[s3 * 2 + q] = thg[s3 * 8 + q];
  {
    const char* bs = wtb + tid * 16;
    #pragma unroll
    for (int j = 0; j < 8; ++j) gload16(bs + j * 4096, smem + j * 4096 + tid * 16);
  }
  __syncthreads();

#define STEP(i, CUR, XC, XN, TC, TN)                                           \
  {                                                                            \
    const int s1_ = ((i) < NSTEP - 1) ? (i) + 1 : (i);                         \
    /* prefetch xc/thr for step+1 FIRST (so B gloads are the newest vmem) */   \
    _Pragma("unroll") for (int mi_ = 0; mi_ < 2; ++mi_)                        \
      _Pragma("unroll") for (int s3_ = 0; s3_ < 2; ++s3_)                      \
        _Pragma("unroll") for (int q_ = 0; q_ < 2; ++q_)                       \
          XN[mi_ * 4 + s3_ * 2 + q_] = (mi_ ? xp1 : xp0)[s1_ * 16 + s3_ * 8 + q_]; \
    _Pragma("unroll") for (int s3_ = 0; s3_ < 2; ++s3_)                        \
      _Pragma("unroll") for (int q_ = 0; q_ < 2; ++q_)                         \
        TN[s3_ * 2 + q_] = thg[s1_ * 16 + s3_ * 8 + q_];                       \
    /* issue B(step+1) into buf^1 */                                           \
    {                                                                          \
      const char* bs_ = wtb + (size_t)s1_ * TILE_B + tid * 16;                 \
      char* bd_ = smem + ((CUR) ^ 1) * 32768 + tid * 16;                       \
      _Pragma("unroll") for (int j_ = 0; j_ < 8; ++j_)                         \
        gload16(bs_ + j_ * 4096, bd_ + j_ * 4096);                             \
    }                                                                          \
    /* A-build(step): inline mask+count + integer hi/lo split (exact R3 bits) */ \
    bf16x8 afh[2][2], afl[2][2];                                               \
    _Pragma("unroll") for (int s3_ = 0; s3_ < 2; ++s3_) {                      \
      const float4 ta_ = TC[s3_ * 2], tb2_ = TC[s3_ * 2 + 1];                  \
      const float ts_[8] = {ta_.x, ta_.y, ta_.z, ta_.w, tb2_.x, tb2_.y, tb2_.z, tb2_.w}; \
      _Pragma("unroll") for (int mi_ = 0; mi_ < 2; ++mi_) {                    \
        const float4 va_ = XC[mi_ * 4 + s3_ * 2], vb_ = XC[mi_ * 4 + s3_ * 2 + 1]; \
        const float xs_[8] = {va_.x, va_.y, va_.z, va_.w, vb_.x, vb_.y, vb_.z, vb_.w}; \
        int c_ = 0;                                                            \
        _Pragma("unroll") for (int e_ = 0; e_ < 8; ++e_) {                     \
          bool k_ = fabsf(xs_[e_]) > ts_[e_];                                  \
          c_ += k_ ? 1 : 0;                                                    \
          float a_ = k_ ? xs_[e_] : 0.0f;                                      \
          unsigned u_ = __builtin_bit_cast(unsigned, a_);                      \
          unsigned rr_ = u_ + 0x7fffu + ((u_ >> 16) & 1u);                     \
          afh[mi_][s3_][e_] = (short)(rr_ >> 16);                              \
          float hf_ = __builtin_bit_cast(float, rr_ & 0xffff0000u);            \
          afl[mi_][s3_][e_] = (short)(__builtin_bit_cast(unsigned, a_ - hf_) >> 16); \
        }                                                                      \
        if (mi_) cnt1 += c_; else cnt0 += c_;                                  \
      }                                                                        \
    }                                                                          \
    /* drain B(step): 12 xc/thr + 8 B(step+1) newer -> vmcnt(20) */            \
    asm volatile("s_waitcnt vmcnt(20)" ::: "memory");                          \
    __builtin_amdgcn_sched_barrier(0);                                         \
    __builtin_amdgcn_s_barrier();                                              \
    __builtin_amdgcn_s_setprio(1);                                             \
    {                                                                          \
      const char* bb_ = smem + (CUR) * 32768;                                  \
      _Pragma("unroll") for (int s3_ = 0; s3_ < 2; ++s3_) {                    \
        _Pragma("unroll") for (int ni_ = 0; ni_ < 4; ++ni_) {                  \
          const int o_ = wc * 64 + ni_ * 16 + l15;                             \
          const int ad_ = o_ * 128 + (((s3_ * 64) + l4 * 16) ^ ((o_ & 7) << 4)); \
          bf16x8 bh_ = *(const bf16x8*)(bb_ + ad_);                            \
          bf16x8 bl_ = *(const bf16x8*)(bb_ + 16384 + ad_);                    \
          _Pragma("unroll") for (int mi_ = 0; mi_ < 2; ++mi_) {                \
            acc[mi_][ni_] = __builtin_amdgcn_mfma_f32_16x16x32_bf16(afh[mi_][s3_], bh_, acc[mi_][ni_], 0, 0, 0); \
            acc[mi_][ni_] = __builtin_amdgcn_mfma_f32_16x16x32_bf16(afh[mi_][s3_], bl_, acc[mi_][ni_], 0, 0, 0); \
            acc[mi_][ni_] = __builtin_amdgcn_mfma_f32_16x16x32_bf16(afl[mi_][s3_], bh_, acc[mi_][ni_], 0, 0, 0); \
          }                                                                    \
        }                                                                      \
      }                                                                        \
    }                                                                          \
    __builtin_amdgcn_s_setprio(0);                                             \
    __builtin_amdgcn_s_barrier();                                              \
  }

  for (int sp = 0; sp < NSTEP; sp += 2) {
    STEP(sp, 0, xA, xB, tA, tB);
    STEP(sp + 1, 1, xB, xA, tB, tA);
  }
#undef STEP

  // ---- mask-count reduce: rows counted once among wc==0 waves ----
  cnt0 += __shfl_xor(cnt0, 16);
  cnt0 += __shfl_xor(cnt0, 32);
  cnt1 += __shfl_xor(cnt1, 16);
  cnt1 += __shfl_xor(cnt1, 32);
  if (wc == 0 && l4 == 0 && lane < 16) {
    atomicAdd(&counts[r0], cnt0);
    atomicAdd(&counts[r1], cnt1);
  }

  // ---- epilogue: y = acc + (post_mu + bias); C/D layout m89-verified ----
  #pragma unroll
  for (int ni = 0; ni < 4; ++ni) {
    const int o = ocol0 + wc * 64 + ni * 16 + l15;
    const float pv = pmb[o];
    #pragma unroll
    for (int mi = 0; mi < 2; ++mi) {
      const int row0 = trow0 + wr * 32 + mi * 16 + l4 * 4;
      #pragma unroll
      for (int r = 0; r < 4; ++r) {
        y[(size_t)(row0 + r) * O_DIM + o] = acc[mi][ni][r] + pv;
      }
    }
  }
}

// k5: flops outputs. flops_sparse = 16777216 * cnt/(64*2048) = 128*cnt (exact).
__global__ void cwic_fin(const int* __restrict__ counts, float* __restrict__ outF) {
  int t = blockIdx.x * 256 + threadIdx.x;
  outF[t] = 16777216.0f;
  outF[T_TOK + t] = 128.0f * (float)counts[t];
}

extern "C" void kernel_launch(void* const* d_in, const int* in_sizes, int n_in,
                              void* d_out, int out_size, void* d_ws, size_t ws_size,
                              hipStream_t stream) {
  const float* x = (const float*)d_in[0];
  const float* w = (const float*)d_in[1];
  const float* bias = (const float*)d_in[2];
  const float* thresholds = (const float*)d_in[3];
  const float* mu = (const float*)d_in[4];
  const float* stdv = (const float*)d_in[5];
  float* y = (float*)d_out;

  char* ws = (char*)d_ws;
  char* wt = ws + WT_OFF;
  float* xc = (float*)(ws + XC_OFF);
  float* thrs = (float*)(ws + THR_OFF);
  float* pm_part = (float*)(ws + PM_OFF);
  float* pmb = (float*)(ws + PMB_OFF);
  int* counts = (int*)(ws + CNT_OFF);

  cwic_init<<<(NSTR * I_DIM) / 256, 256, 0, stream>>>(thresholds, stdv, thrs, counts);
  cwic_xc<<<1024, 256, 0, stream>>>(x, mu, xc);
  cwic_wprep<<<NSTR * NSTEP, 256, 0, stream>>>(w, mu, wt, pm_part);
  cwic_pmb<<<32, 256, 0, stream>>>(pm_part, bias, pmb);
  cwic_gemm5<<<512, 256, 65536, stream>>>(xc, wt, thrs, pmb, y, counts);
  cwic_fin<<<2, 256, 0, stream>>>(counts, y + (size_t)T_TOK * O_DIM);
}